// Round 1
// baseline (396.590 us; speedup 1.0000x reference)
//
#include <hip/hip_runtime.h>
#include <hip/hip_bf16.h>

// Color_Attention: transposed (channel) attention.
// Algebraic restructure:
//   G_ic = I*C^T, G_cc = C*C^T, G_ii = I*I^T   (192x192 per batch, K=16384)
//   H = Wq*G_ci (via G_ic rows), A_pre = H*Wk^T
//   nq = diag(Wq*G_cc*Wq^T), nk = diag(Wk*G_ii*Wk^T)
//   attn = softmax over head-diagonal 24x24 blocks of A_pre/(nq*nk)
//   P = Wo * blockdiag(attn) * Wv   (192x192 per batch)
//   out = P @ input                  (the only big output GEMM)

typedef __attribute__((ext_vector_type(4))) float f32x4;
typedef __attribute__((ext_vector_type(8))) short short8;

#define MFMA16(a, b, c) __builtin_amdgcn_mfma_f32_16x16x32_bf16((a), (b), (c), 0, 0, 0)

__device__ __forceinline__ unsigned int pack_rne(float a, float b) {
  unsigned int ua = __float_as_uint(a), ub = __float_as_uint(b);
  ua += 0x7fffu + ((ua >> 16) & 1u);
  ub += 0x7fffu + ((ub >> 16) & 1u);
  return (ua >> 16) | (ub & 0xffff0000u);
}
__device__ __forceinline__ unsigned short bf16u_rne(float x) {
  unsigned int u = __float_as_uint(x);
  u += 0x7fffu + ((u >> 16) & 1u);
  return (unsigned short)(u >> 16);
}
union S8U { short8 s; unsigned int u[4]; };
__device__ __forceinline__ short8 load_cvt8(const float* p) {
  f32x4 x = *(const f32x4*)p;
  f32x4 y = *(const f32x4*)(p + 4);
  S8U r;
  r.u[0] = pack_rne(x[0], x[1]);
  r.u[1] = pack_rne(x[2], x[3]);
  r.u[2] = pack_rne(y[0], y[1]);
  r.u[3] = pack_rne(y[2], y[3]);
  return r.s;
}

#define HW 16384
#define CDIM 192
#define NB 8
#define NCHUNK 32
#define KCHUNK (HW / NCHUNK)  // 512

// ---------------- Kernel 0: transpose Wv -> bf16 WvT[j][c'] ----------------
__global__ void k0_wvt(const float* __restrict__ Wv, unsigned short* __restrict__ WvT) {
  int idx = blockIdx.x * 256 + threadIdx.x;
  if (idx < CDIM * CDIM) {
    int j = idx / CDIM, cp = idx % CDIM;
    WvT[idx] = bf16u_rne(Wv[(size_t)cp * CDIM + j]);
  }
}

// ---------------- Kernel 1: Gram matrices (atomic fp32 accumulate) ----------
// grid (NCHUNK, 8, 3); type 0: X=input,Y=color (G_ic); 1: C*C^T; 2: I*I^T
__global__ __launch_bounds__(256) void gram_k(const float* __restrict__ input,
                                              const float* __restrict__ color,
                                              float* __restrict__ G) {
  const int chunk = blockIdx.x, b = blockIdx.y, type = blockIdx.z;
  const size_t base = (size_t)b * CDIM * HW;
  const float* X = ((type == 1) ? color : input) + base;
  const float* Y = ((type == 2) ? input : color) + base;
  const int tid = threadIdx.x, wave = tid >> 6, lane = tid & 63;
  const int l15 = lane & 15, lg = lane >> 4;
  const int row0 = wave * 48;
  const int k0 = chunk * KCHUNK + lg * 8;

  f32x4 acc[3][12];
#pragma unroll
  for (int t = 0; t < 3; t++)
#pragma unroll
    for (int j = 0; j < 12; j++) acc[t][j] = (f32x4){0.f, 0.f, 0.f, 0.f};

  const float* ap = X + (size_t)(row0 + l15) * HW + k0;
  const float* bp = Y + (size_t)l15 * HW + k0;
  for (int ks = 0; ks < KCHUNK; ks += 32) {
    short8 afr[3];
#pragma unroll
    for (int t = 0; t < 3; t++) afr[t] = load_cvt8(ap + (size_t)t * 16 * HW + ks);
#pragma unroll
    for (int tj = 0; tj < 12; tj++) {
      short8 bfr = load_cvt8(bp + (size_t)tj * 16 * HW + ks);
#pragma unroll
      for (int t = 0; t < 3; t++) acc[t][tj] = MFMA16(afr[t], bfr, acc[t][tj]);
    }
  }
  float* Gb = G + ((size_t)type * NB + b) * (CDIM * CDIM);
#pragma unroll
  for (int t = 0; t < 3; t++) {
    const int m0 = row0 + t * 16 + lg * 4;
#pragma unroll
    for (int tj = 0; tj < 12; tj++) {
      const int n = tj * 16 + l15;
#pragma unroll
      for (int r = 0; r < 4; r++) atomicAdd(&Gb[(size_t)(m0 + r) * CDIM + n], acc[t][tj][r]);
    }
  }
}

// ---------------- Kernel 2a: A_pre (type0), nq (type1), nk (type2) ----------
// grid (8, 3)
__global__ __launch_bounds__(256) void k2a(const float* __restrict__ G,
                                           const float* __restrict__ Wq,
                                           const float* __restrict__ Wk,
                                           float* __restrict__ A_pre,
                                           float* __restrict__ nqk) {
  const int b = blockIdx.x, type = blockIdx.y;
  __shared__ __align__(16) unsigned short Hs[192][200];
  const int tid = threadIdx.x, wave = tid >> 6, lane = tid & 63;
  const int l15 = lane & 15, lg = lane >> 4, row0 = wave * 48;
  const float* W1 = (type == 2) ? Wk : Wq;
  const float* Gm = G + ((size_t)type * NB + b) * (CDIM * CDIM);

  f32x4 acc[3][12];
#pragma unroll
  for (int t = 0; t < 3; t++)
#pragma unroll
    for (int j = 0; j < 12; j++) acc[t][j] = (f32x4){0.f, 0.f, 0.f, 0.f};

  for (int ks = 0; ks < 192; ks += 32) {
    short8 afr[3];
#pragma unroll
    for (int t = 0; t < 3; t++)
      afr[t] = load_cvt8(W1 + (size_t)(row0 + t * 16 + l15) * CDIM + ks + lg * 8);
#pragma unroll
    for (int tj = 0; tj < 12; tj++) {
      short8 bfr = load_cvt8(Gm + (size_t)(tj * 16 + l15) * CDIM + ks + lg * 8);
#pragma unroll
      for (int t = 0; t < 3; t++) acc[t][tj] = MFMA16(afr[t], bfr, acc[t][tj]);
    }
  }
  // T -> LDS (bf16)
#pragma unroll
  for (int t = 0; t < 3; t++)
#pragma unroll
    for (int tj = 0; tj < 12; tj++)
#pragma unroll
      for (int r = 0; r < 4; r++)
        Hs[row0 + t * 16 + lg * 4 + r][tj * 16 + l15] = bf16u_rne(acc[t][tj][r]);
  __syncthreads();

  if (type == 0) {
    f32x4 a2[3][12];
#pragma unroll
    for (int t = 0; t < 3; t++)
#pragma unroll
      for (int j = 0; j < 12; j++) a2[t][j] = (f32x4){0.f, 0.f, 0.f, 0.f};
    for (int ks = 0; ks < 192; ks += 32) {
      short8 afr[3];
#pragma unroll
      for (int t = 0; t < 3; t++)
        afr[t] = *(const short8*)&Hs[row0 + t * 16 + l15][ks + lg * 8];
#pragma unroll
      for (int tj = 0; tj < 12; tj++) {
        short8 bfr = load_cvt8(Wk + (size_t)(tj * 16 + l15) * CDIM + ks + lg * 8);
#pragma unroll
        for (int t = 0; t < 3; t++) a2[t][tj] = MFMA16(afr[t], bfr, a2[t][tj]);
      }
    }
    float* Ab = A_pre + (size_t)b * CDIM * CDIM;
#pragma unroll
    for (int t = 0; t < 3; t++)
#pragma unroll
      for (int tj = 0; tj < 12; tj++)
#pragma unroll
        for (int r = 0; r < 4; r++)
          Ab[(size_t)(row0 + t * 16 + lg * 4 + r) * CDIM + tj * 16 + l15] = a2[t][tj][r];
  } else {
    // only diagonal tiles -> row norms
    f32x4 a2[3];
#pragma unroll
    for (int t = 0; t < 3; t++) a2[t] = (f32x4){0.f, 0.f, 0.f, 0.f};
    for (int ks = 0; ks < 192; ks += 32) {
#pragma unroll
      for (int t = 0; t < 3; t++) {
        short8 afr = *(const short8*)&Hs[row0 + t * 16 + l15][ks + lg * 8];
        short8 bfr = load_cvt8(W1 + (size_t)(row0 + t * 16 + l15) * CDIM + ks + lg * 8);
        a2[t] = MFMA16(afr, bfr, a2[t]);
      }
    }
    float* dst = nqk + ((size_t)(type - 1) * NB + b) * CDIM;
#pragma unroll
    for (int t = 0; t < 3; t++)
#pragma unroll
      for (int r = 0; r < 4; r++)
        if (lg * 4 + r == l15) dst[row0 + t * 16 + l15] = a2[t][r];
  }
}

// ---------------- Kernel 2b: per-head softmax ----------------
// grid (8); threads: h = tid>>5 (8 heads), r = tid&31 (row, <24 active)
__global__ void k2b(const float* __restrict__ A_pre, const float* __restrict__ nqk,
                    float* __restrict__ attnw) {
  const int b = blockIdx.x, tid = threadIdx.x;
  const int h = tid >> 5, r = tid & 31;
  if (r >= 24) return;
  const float* Ab = A_pre + (size_t)b * CDIM * CDIM;
  const float* nq = nqk + (size_t)b * CDIM;
  const float* nk = nqk + (size_t)(NB + b) * CDIM;
  const int c = h * 24 + r;
  const float qn = rsqrtf(fmaxf(nq[c], 1e-24f));
  float e[24];
  float mx = -1e30f;
#pragma unroll
  for (int d = 0; d < 24; d++) {
    float kn = rsqrtf(fmaxf(nk[h * 24 + d], 1e-24f));
    float l = Ab[(size_t)c * CDIM + h * 24 + d] * qn * kn;
    e[d] = l;
    mx = fmaxf(mx, l);
  }
  float s = 0.f;
#pragma unroll
  for (int d = 0; d < 24; d++) {
    float x = __expf(e[d] - mx);
    e[d] = x;
    s += x;
  }
  const float inv = 1.0f / s;
  float* dst = attnw + (((size_t)b * NB + h) * 24 + r) * 24;
#pragma unroll
  for (int d = 0; d < 24; d++) dst[d] = e[d] * inv;
}

// ---------------- Kernel 3: P = Wo * blockdiag(attn) * Wv  (bf16 out) -------
// grid (8)
__global__ __launch_bounds__(256) void k3(const float* __restrict__ attnw,
                                          const float* __restrict__ Wo,
                                          const unsigned short* __restrict__ WvT,
                                          unsigned short* __restrict__ Pbf) {
  const int b = blockIdx.x;
  __shared__ __align__(16) unsigned short AT[192][200];
  __shared__ __align__(16) unsigned short Ms[192][200];
  const int tid = threadIdx.x, wave = tid >> 6, lane = tid & 63;
  const int l15 = lane & 15, lg = lane >> 4, row0 = wave * 48;

  unsigned int* ATu = (unsigned int*)&AT[0][0];
  for (int i = tid; i < 192 * 100; i += 256) ATu[i] = 0u;
  __syncthreads();
  const float* at = attnw + (size_t)b * NB * 24 * 24;
  for (int i = tid; i < 4608; i += 256) {
    int h = i / 576, rem = i % 576, c = rem / 24, d = rem % 24;
    AT[h * 24 + d][h * 24 + c] = bf16u_rne(at[(h * 24 + c) * 24 + d]);
  }
  __syncthreads();

  f32x4 acc[3][12];
#pragma unroll
  for (int t = 0; t < 3; t++)
#pragma unroll
    for (int j = 0; j < 12; j++) acc[t][j] = (f32x4){0.f, 0.f, 0.f, 0.f};
  for (int ks = 0; ks < 192; ks += 32) {
    short8 afr[3];
#pragma unroll
    for (int t = 0; t < 3; t++)
      afr[t] = load_cvt8(Wo + (size_t)(row0 + t * 16 + l15) * CDIM + ks + lg * 8);
#pragma unroll
    for (int tj = 0; tj < 12; tj++) {
      short8 bfr = *(const short8*)&AT[tj * 16 + l15][ks + lg * 8];
#pragma unroll
      for (int t = 0; t < 3; t++) acc[t][tj] = MFMA16(afr[t], bfr, acc[t][tj]);
    }
  }
#pragma unroll
  for (int t = 0; t < 3; t++)
#pragma unroll
    for (int tj = 0; tj < 12; tj++)
#pragma unroll
      for (int r = 0; r < 4; r++)
        Ms[row0 + t * 16 + lg * 4 + r][tj * 16 + l15] = bf16u_rne(acc[t][tj][r]);
  __syncthreads();

  f32x4 a2[3][12];
#pragma unroll
  for (int t = 0; t < 3; t++)
#pragma unroll
    for (int j = 0; j < 12; j++) a2[t][j] = (f32x4){0.f, 0.f, 0.f, 0.f};
  for (int ks = 0; ks < 192; ks += 32) {
    short8 afr[3];
#pragma unroll
    for (int t = 0; t < 3; t++)
      afr[t] = *(const short8*)&Ms[row0 + t * 16 + l15][ks + lg * 8];
#pragma unroll
    for (int tj = 0; tj < 12; tj++) {
      short8 bfr = *(const short8*)(WvT + (size_t)(tj * 16 + l15) * CDIM + ks + lg * 8);
#pragma unroll
      for (int t = 0; t < 3; t++) a2[t][tj] = MFMA16(afr[t], bfr, a2[t][tj]);
    }
  }
  unsigned short* Pb = Pbf + (size_t)b * CDIM * CDIM;
#pragma unroll
  for (int t = 0; t < 3; t++)
#pragma unroll
    for (int tj = 0; tj < 12; tj++)
#pragma unroll
      for (int r = 0; r < 4; r++)
        Pb[(size_t)(row0 + t * 16 + lg * 4 + r) * CDIM + tj * 16 + l15] = bf16u_rne(a2[t][tj][r]);
}

// ---------------- Kernel D: out = P @ input  ----------------
// grid (128, 8): 128-column chunks of the 16384 spatial dim
__global__ __launch_bounds__(256) void kD(const unsigned short* __restrict__ Pbf,
                                          const float* __restrict__ input,
                                          float* __restrict__ out) {
  const int nchunk = blockIdx.x, b = blockIdx.y;
  const int n0 = nchunk * 128;
  __shared__ unsigned short Bs[192][130];  // [j][n], 260B rows: conflict-free reads
  const int tid = threadIdx.x, wave = tid >> 6, lane = tid & 63;
  const int l15 = lane & 15, lg = lane >> 4, row0 = wave * 48;

  {
    const int q = tid & 31;   // n-quad
    const int j0 = tid >> 5;  // 0..7
    const float* src = input + (size_t)b * CDIM * HW + n0 + q * 4;
    char* bsb = (char*)&Bs[0][0];
#pragma unroll 4
    for (int j = j0; j < CDIM; j += 8) {
      f32x4 v = *(const f32x4*)(src + (size_t)j * HW);
      unsigned int p0 = pack_rne(v[0], v[1]);
      unsigned int p1 = pack_rne(v[2], v[3]);
      const int byte = j * 260 + q * 8;
      *(unsigned int*)(bsb + byte) = p0;
      *(unsigned int*)(bsb + byte + 4) = p1;
    }
  }
  __syncthreads();

  f32x4 acc[3][8];
#pragma unroll
  for (int t = 0; t < 3; t++)
#pragma unroll
    for (int j = 0; j < 8; j++) acc[t][j] = (f32x4){0.f, 0.f, 0.f, 0.f};

  const unsigned short* Pb = Pbf + (size_t)b * CDIM * CDIM;
  for (int ks = 0; ks < 192; ks += 32) {
    short8 afr[3];
#pragma unroll
    for (int t = 0; t < 3; t++)
      afr[t] = *(const short8*)(Pb + (size_t)(row0 + t * 16 + l15) * CDIM + ks + lg * 8);
#pragma unroll
    for (int tn = 0; tn < 8; tn++) {
      S8U bf;
#pragma unroll
      for (int e2 = 0; e2 < 4; e2++) {
        const int k = ks + lg * 8 + e2 * 2;
        unsigned int h0 = Bs[k][tn * 16 + l15];
        unsigned int h1 = Bs[k + 1][tn * 16 + l15];
        bf.u[e2] = h0 | (h1 << 16);
      }
#pragma unroll
      for (int t = 0; t < 3; t++) acc[t][tn] = MFMA16(afr[t], bf.s, acc[t][tn]);
    }
  }
  float* ob = out + (size_t)b * CDIM * HW + n0;
#pragma unroll
  for (int t = 0; t < 3; t++)
#pragma unroll
    for (int tn = 0; tn < 8; tn++)
#pragma unroll
      for (int r = 0; r < 4; r++) {
        const int m = row0 + t * 16 + lg * 4 + r;
        ob[(size_t)m * HW + tn * 16 + l15] = acc[t][tn][r];
      }
}

// ---------------- launch ----------------
extern "C" void kernel_launch(void* const* d_in, const int* in_sizes, int n_in,
                              void* d_out, int out_size, void* d_ws, size_t ws_size,
                              hipStream_t stream) {
  const float* input = (const float*)d_in[0];
  const float* color = (const float*)d_in[1];
  const float* Wq = (const float*)d_in[2];
  const float* Wk = (const float*)d_in[3];
  const float* Wv = (const float*)d_in[4];
  const float* Wo = (const float*)d_in[5];
  float* out = (float*)d_out;
  char* ws = (char*)d_ws;

  const size_t OFF_G = 0;                        // 3*8*192*192*4 = 3538944
  const size_t OFF_APRE = 3538944;               // 8*192*192*4  = 1179648
  const size_t OFF_NQK = OFF_APRE + 1179648;     // 2*8*192*4    = 12288
  const size_t OFF_ATT = OFF_NQK + 12288;        // 8*8*24*24*4  = 147456
  const size_t OFF_WVT = OFF_ATT + 147456;       // 192*192*2    = 73728
  const size_t OFF_PBF = OFF_WVT + 73728;        // 8*192*192*2  = 589824

  float* G = (float*)(ws + OFF_G);
  float* A_pre = (float*)(ws + OFF_APRE);
  float* nqk = (float*)(ws + OFF_NQK);
  float* attnw = (float*)(ws + OFF_ATT);
  unsigned short* WvT = (unsigned short*)(ws + OFF_WVT);
  unsigned short* Pbf = (unsigned short*)(ws + OFF_PBF);

  hipMemsetAsync(G, 0, 3 * NB * CDIM * CDIM * sizeof(float), stream);
  k0_wvt<<<dim3(144), dim3(256), 0, stream>>>(Wv, WvT);
  gram_k<<<dim3(NCHUNK, NB, 3), dim3(256), 0, stream>>>(input, color, G);
  k2a<<<dim3(NB, 3), dim3(256), 0, stream>>>(G, Wq, Wk, A_pre, nqk);
  k2b<<<dim3(NB), dim3(256), 0, stream>>>(A_pre, nqk, attnw);
  k3<<<dim3(NB), dim3(256), 0, stream>>>(attnw, Wo, WvT, Pbf);
  kD<<<dim3(HW / 128, NB), dim3(256), 0, stream>>>(Pbf, input, out);
}

// Round 2
// 286.485 us; speedup vs baseline: 1.3843x; 1.3843x over previous
//
#include <hip/hip_runtime.h>
#include <hip/hip_bf16.h>

// Color_Attention: transposed (channel) attention.
// Algebraic restructure:
//   G_ic = I*C^T, G_cc = C*C^T, G_ii = I*I^T   (192x192 per batch, K=16384)
//   H = Wq*G_ci (via G_ic rows), A_pre = H*Wk^T
//   nq = diag(Wq*G_cc*Wq^T), nk = diag(Wk*G_ii*Wk^T)
//   attn = softmax over head-diagonal 24x24 blocks of A_pre/(nq*nk)
//   P = Wo * blockdiag(attn) * Wv   (192x192 per batch)
//   out = P @ input                  (the only big output GEMM)

typedef __attribute__((ext_vector_type(4))) float f32x4;
typedef __attribute__((ext_vector_type(8))) short short8;

#define MFMA16(a, b, c) __builtin_amdgcn_mfma_f32_16x16x32_bf16((a), (b), (c), 0, 0, 0)

__device__ __forceinline__ unsigned int pack_rne(float a, float b) {
  unsigned int ua = __float_as_uint(a), ub = __float_as_uint(b);
  ua += 0x7fffu + ((ua >> 16) & 1u);
  ub += 0x7fffu + ((ub >> 16) & 1u);
  return (ua >> 16) | (ub & 0xffff0000u);
}
__device__ __forceinline__ unsigned short bf16u_rne(float x) {
  unsigned int u = __float_as_uint(x);
  u += 0x7fffu + ((u >> 16) & 1u);
  return (unsigned short)(u >> 16);
}
union S8U { short8 s; unsigned int u[4]; };
__device__ __forceinline__ short8 load_cvt8(const float* p) {
  f32x4 x = *(const f32x4*)p;
  f32x4 y = *(const f32x4*)(p + 4);
  S8U r;
  r.u[0] = pack_rne(x[0], x[1]);
  r.u[1] = pack_rne(x[2], x[3]);
  r.u[2] = pack_rne(y[0], y[1]);
  r.u[3] = pack_rne(y[2], y[3]);
  return r.s;
}

#define HW 16384
#define CDIM 192
#define NB 8
#define KC 64        // chunk width (columns of spatial dim per staged tile)
#define NSTRIP 32    // strips; each strip covers CPB chunks
#define CPB 8        // chunks per block (NSTRIP*CPB*KC == HW)

// ---------------- Kernel 0: transpose Wv -> bf16 WvT[j][c'] ----------------
__global__ void k0_wvt(const float* __restrict__ Wv, unsigned short* __restrict__ WvT) {
  int idx = blockIdx.x * 256 + threadIdx.x;
  if (idx < CDIM * CDIM) {
    int j = idx / CDIM, cp = idx % CDIM;
    WvT[idx] = bf16u_rne(Wv[(size_t)cp * CDIM + j]);
  }
}

// ---------------- Kernel 1: Gram matrices, staged-LDS version ----------
// One staged tile = 192 rows x 64 cols bf16 (128 B/row), XOR-swizzled:
//   byte(row, colbyte) = row*128 + (colbyte ^ ((row&7)<<4))
// Conflict-free for both b64 staging writes and b128 fragment reads; 16B aligned.
__device__ __forceinline__ void gram_one(const float* __restrict__ X,
                                         const float* __restrict__ Y, int dual,
                                         float* __restrict__ Gb,
                                         char* tXb, char* tYb,
                                         int strip, int tid) {
  const int wave = tid >> 6, lane = tid & 63;
  const int l15 = lane & 15, lg = lane >> 4, row0 = wave * 48;
  const int sw = (l15 & 7) << 4;        // compute-phase swizzle (row&7 == l15&7)
  const int srow = tid >> 4;            // staging row-in-group (0..15)
  const int scol = (tid & 15) * 4;      // staging float col
  const int ssw = (srow & 7) << 4;      // staging swizzle ((16*rnd+srow)&7 == srow&7)
  const int scb = scol * 2;             // staging col byte (bf16)

  f32x4 acc[3][12];
#pragma unroll
  for (int t = 0; t < 3; t++)
#pragma unroll
    for (int j = 0; j < 12; j++) acc[t][j] = (f32x4){0.f, 0.f, 0.f, 0.f};

  for (int c = strip * CPB; c < strip * CPB + CPB; ++c) {
    // ---- stage X tile ----
    {
      const float* xp = X + (size_t)srow * HW + c * KC + scol;
      f32x4 vx[12];
#pragma unroll
      for (int r = 0; r < 12; r++) vx[r] = *(const f32x4*)(xp + (size_t)r * 16 * HW);
#pragma unroll
      for (int r = 0; r < 12; r++) {
        unsigned long long p =
            (unsigned long long)pack_rne(vx[r][0], vx[r][1]) |
            ((unsigned long long)pack_rne(vx[r][2], vx[r][3]) << 32);
        *(unsigned long long*)(tXb + (16 * r + srow) * 128 + (scb ^ ssw)) = p;
      }
    }
    if (dual) {
      const float* yp = Y + (size_t)srow * HW + c * KC + scol;
      f32x4 vy[12];
#pragma unroll
      for (int r = 0; r < 12; r++) vy[r] = *(const f32x4*)(yp + (size_t)r * 16 * HW);
#pragma unroll
      for (int r = 0; r < 12; r++) {
        unsigned long long p =
            (unsigned long long)pack_rne(vy[r][0], vy[r][1]) |
            ((unsigned long long)pack_rne(vy[r][2], vy[r][3]) << 32);
        *(unsigned long long*)(tYb + (16 * r + srow) * 128 + (scb ^ ssw)) = p;
      }
    }
    __syncthreads();

    // ---- compute from LDS ----
    const char* Bt = dual ? tYb : tXb;
#pragma unroll
    for (int ks = 0; ks < 2; ks++) {
      const int cbs = (ks * 64 + lg * 16) ^ sw;
      short8 afr[3];
#pragma unroll
      for (int t = 0; t < 3; t++)
        afr[t] = *(const short8*)(tXb + (row0 + t * 16 + l15) * 128 + cbs);
#pragma unroll
      for (int tj = 0; tj < 12; tj++) {
        short8 bfr = *(const short8*)(Bt + (tj * 16 + l15) * 128 + cbs);
#pragma unroll
        for (int t = 0; t < 3; t++) acc[t][tj] = MFMA16(afr[t], bfr, acc[t][tj]);
      }
    }
    __syncthreads();
  }

  // ---- flush (atomic fp32) ----
#pragma unroll
  for (int t = 0; t < 3; t++) {
    const int m0 = row0 + t * 16 + lg * 4;
#pragma unroll
    for (int tj = 0; tj < 12; tj++) {
      const int n = tj * 16 + l15;
#pragma unroll
      for (int r = 0; r < 4; r++) atomicAdd(&Gb[(size_t)(m0 + r) * CDIM + n], acc[t][tj][r]);
    }
  }
}

// grid (NSTRIP, NB, 2): z=0 -> G_ic (stages I and C); z=1 -> G_cc then G_ii
__global__ __launch_bounds__(256) void gram_k(const float* __restrict__ input,
                                              const float* __restrict__ color,
                                              float* __restrict__ G) {
  __shared__ __align__(16) char tXb[192 * 128];
  __shared__ __align__(16) char tYb[192 * 128];
  const int strip = blockIdx.x, b = blockIdx.y, z = blockIdx.z;
  const int tid = threadIdx.x;
  const size_t base = (size_t)b * CDIM * HW;
  if (z == 0) {
    gram_one(input + base, color + base, 1, G + (size_t)b * CDIM * CDIM, tXb, tYb, strip, tid);
  } else {
    gram_one(color + base, color + base, 0, G + ((size_t)NB + b) * CDIM * CDIM, tXb, tYb, strip, tid);
    gram_one(input + base, input + base, 0, G + ((size_t)2 * NB + b) * CDIM * CDIM, tXb, tYb, strip, tid);
  }
}

// ---------------- Kernel 2a: A_pre (type0), nq (type1), nk (type2) ----------
// grid (8, 3)
__global__ __launch_bounds__(256) void k2a(const float* __restrict__ G,
                                           const float* __restrict__ Wq,
                                           const float* __restrict__ Wk,
                                           float* __restrict__ A_pre,
                                           float* __restrict__ nqk) {
  const int b = blockIdx.x, type = blockIdx.y;
  __shared__ __align__(16) unsigned short Hs[192][200];
  const int tid = threadIdx.x, wave = tid >> 6, lane = tid & 63;
  const int l15 = lane & 15, lg = lane >> 4, row0 = wave * 48;
  const float* W1 = (type == 2) ? Wk : Wq;
  const float* Gm = G + ((size_t)type * NB + b) * (CDIM * CDIM);

  f32x4 acc[3][12];
#pragma unroll
  for (int t = 0; t < 3; t++)
#pragma unroll
    for (int j = 0; j < 12; j++) acc[t][j] = (f32x4){0.f, 0.f, 0.f, 0.f};

  for (int ks = 0; ks < 192; ks += 32) {
    short8 afr[3];
#pragma unroll
    for (int t = 0; t < 3; t++)
      afr[t] = load_cvt8(W1 + (size_t)(row0 + t * 16 + l15) * CDIM + ks + lg * 8);
#pragma unroll
    for (int tj = 0; tj < 12; tj++) {
      short8 bfr = load_cvt8(Gm + (size_t)(tj * 16 + l15) * CDIM + ks + lg * 8);
#pragma unroll
      for (int t = 0; t < 3; t++) acc[t][tj] = MFMA16(afr[t], bfr, acc[t][tj]);
    }
  }
  // T -> LDS (bf16)
#pragma unroll
  for (int t = 0; t < 3; t++)
#pragma unroll
    for (int tj = 0; tj < 12; tj++)
#pragma unroll
      for (int r = 0; r < 4; r++)
        Hs[row0 + t * 16 + lg * 4 + r][tj * 16 + l15] = bf16u_rne(acc[t][tj][r]);
  __syncthreads();

  if (type == 0) {
    f32x4 a2[3][12];
#pragma unroll
    for (int t = 0; t < 3; t++)
#pragma unroll
      for (int j = 0; j < 12; j++) a2[t][j] = (f32x4){0.f, 0.f, 0.f, 0.f};
    for (int ks = 0; ks < 192; ks += 32) {
      short8 afr[3];
#pragma unroll
      for (int t = 0; t < 3; t++)
        afr[t] = *(const short8*)&Hs[row0 + t * 16 + l15][ks + lg * 8];
#pragma unroll
      for (int tj = 0; tj < 12; tj++) {
        short8 bfr = load_cvt8(Wk + (size_t)(tj * 16 + l15) * CDIM + ks + lg * 8);
#pragma unroll
        for (int t = 0; t < 3; t++) a2[t][tj] = MFMA16(afr[t], bfr, a2[t][tj]);
      }
    }
    float* Ab = A_pre + (size_t)b * CDIM * CDIM;
#pragma unroll
    for (int t = 0; t < 3; t++)
#pragma unroll
      for (int tj = 0; tj < 12; tj++)
#pragma unroll
        for (int r = 0; r < 4; r++)
          Ab[(size_t)(row0 + t * 16 + lg * 4 + r) * CDIM + tj * 16 + l15] = a2[t][tj][r];
  } else {
    // only diagonal tiles -> row norms
    f32x4 a2[3];
#pragma unroll
    for (int t = 0; t < 3; t++) a2[t] = (f32x4){0.f, 0.f, 0.f, 0.f};
    for (int ks = 0; ks < 192; ks += 32) {
#pragma unroll
      for (int t = 0; t < 3; t++) {
        short8 afr = *(const short8*)&Hs[row0 + t * 16 + l15][ks + lg * 8];
        short8 bfr = load_cvt8(W1 + (size_t)(row0 + t * 16 + l15) * CDIM + ks + lg * 8);
        a2[t] = MFMA16(afr, bfr, a2[t]);
      }
    }
    float* dst = nqk + ((size_t)(type - 1) * NB + b) * CDIM;
#pragma unroll
    for (int t = 0; t < 3; t++)
#pragma unroll
      for (int r = 0; r < 4; r++)
        if (lg * 4 + r == l15) dst[row0 + t * 16 + l15] = a2[t][r];
  }
}

// ---------------- Kernel 2b: per-head softmax ----------------
// grid (8); threads: h = tid>>5 (8 heads), r = tid&31 (row, <24 active)
__global__ void k2b(const float* __restrict__ A_pre, const float* __restrict__ nqk,
                    float* __restrict__ attnw) {
  const int b = blockIdx.x, tid = threadIdx.x;
  const int h = tid >> 5, r = tid & 31;
  if (r >= 24) return;
  const float* Ab = A_pre + (size_t)b * CDIM * CDIM;
  const float* nq = nqk + (size_t)b * CDIM;
  const float* nk = nqk + (size_t)(NB + b) * CDIM;
  const int c = h * 24 + r;
  const float qn = rsqrtf(fmaxf(nq[c], 1e-24f));
  float e[24];
  float mx = -1e30f;
#pragma unroll
  for (int d = 0; d < 24; d++) {
    float kn = rsqrtf(fmaxf(nk[h * 24 + d], 1e-24f));
    float l = Ab[(size_t)c * CDIM + h * 24 + d] * qn * kn;
    e[d] = l;
    mx = fmaxf(mx, l);
  }
  float s = 0.f;
#pragma unroll
  for (int d = 0; d < 24; d++) {
    float x = __expf(e[d] - mx);
    e[d] = x;
    s += x;
  }
  const float inv = 1.0f / s;
  float* dst = attnw + (((size_t)b * NB + h) * 24 + r) * 24;
#pragma unroll
  for (int d = 0; d < 24; d++) dst[d] = e[d] * inv;
}

// ---------------- Kernel 3: P = Wo * blockdiag(attn) * Wv  (bf16 out) -------
// grid (8)
__global__ __launch_bounds__(256) void k3(const float* __restrict__ attnw,
                                          const float* __restrict__ Wo,
                                          const unsigned short* __restrict__ WvT,
                                          unsigned short* __restrict__ Pbf) {
  const int b = blockIdx.x;
  __shared__ __align__(16) unsigned short AT[192][200];
  __shared__ __align__(16) unsigned short Ms[192][200];
  const int tid = threadIdx.x, wave = tid >> 6, lane = tid & 63;
  const int l15 = lane & 15, lg = lane >> 4, row0 = wave * 48;

  unsigned int* ATu = (unsigned int*)&AT[0][0];
  for (int i = tid; i < 192 * 100; i += 256) ATu[i] = 0u;
  __syncthreads();
  const float* at = attnw + (size_t)b * NB * 24 * 24;
  for (int i = tid; i < 4608; i += 256) {
    int h = i / 576, rem = i % 576, c = rem / 24, d = rem % 24;
    AT[h * 24 + d][h * 24 + c] = bf16u_rne(at[(h * 24 + c) * 24 + d]);
  }
  __syncthreads();

  f32x4 acc[3][12];
#pragma unroll
  for (int t = 0; t < 3; t++)
#pragma unroll
    for (int j = 0; j < 12; j++) acc[t][j] = (f32x4){0.f, 0.f, 0.f, 0.f};
  for (int ks = 0; ks < 192; ks += 32) {
    short8 afr[3];
#pragma unroll
    for (int t = 0; t < 3; t++)
      afr[t] = load_cvt8(Wo + (size_t)(row0 + t * 16 + l15) * CDIM + ks + lg * 8);
#pragma unroll
    for (int tj = 0; tj < 12; tj++) {
      short8 bfr = *(const short8*)&AT[tj * 16 + l15][ks + lg * 8];
#pragma unroll
      for (int t = 0; t < 3; t++) acc[t][tj] = MFMA16(afr[t], bfr, acc[t][tj]);
    }
  }
#pragma unroll
  for (int t = 0; t < 3; t++)
#pragma unroll
    for (int tj = 0; tj < 12; tj++)
#pragma unroll
      for (int r = 0; r < 4; r++)
        Ms[row0 + t * 16 + lg * 4 + r][tj * 16 + l15] = bf16u_rne(acc[t][tj][r]);
  __syncthreads();

  f32x4 a2[3][12];
#pragma unroll
  for (int t = 0; t < 3; t++)
#pragma unroll
    for (int j = 0; j < 12; j++) a2[t][j] = (f32x4){0.f, 0.f, 0.f, 0.f};
  for (int ks = 0; ks < 192; ks += 32) {
    short8 afr[3];
#pragma unroll
    for (int t = 0; t < 3; t++)
      afr[t] = *(const short8*)&Ms[row0 + t * 16 + l15][ks + lg * 8];
#pragma unroll
    for (int tj = 0; tj < 12; tj++) {
      short8 bfr = *(const short8*)(WvT + (size_t)(tj * 16 + l15) * CDIM + ks + lg * 8);
#pragma unroll
      for (int t = 0; t < 3; t++) a2[t][tj] = MFMA16(afr[t], bfr, a2[t][tj]);
    }
  }
  unsigned short* Pb = Pbf + (size_t)b * CDIM * CDIM;
#pragma unroll
  for (int t = 0; t < 3; t++)
#pragma unroll
    for (int tj = 0; tj < 12; tj++)
#pragma unroll
      for (int r = 0; r < 4; r++)
        Pb[(size_t)(row0 + t * 16 + lg * 4 + r) * CDIM + tj * 16 + l15] = bf16u_rne(a2[t][tj][r]);
}

// ---------------- Kernel D: out = P @ input  ----------------
// grid (128, 8): 128-column chunks of the 16384 spatial dim
__global__ __launch_bounds__(256) void kD(const unsigned short* __restrict__ Pbf,
                                          const float* __restrict__ input,
                                          float* __restrict__ out) {
  const int nchunk = blockIdx.x, b = blockIdx.y;
  const int n0 = nchunk * 128;
  __shared__ unsigned short Bs[192][130];  // [j][n], 260B rows: conflict-free reads
  const int tid = threadIdx.x, wave = tid >> 6, lane = tid & 63;
  const int l15 = lane & 15, lg = lane >> 4, row0 = wave * 48;

  {
    const int q = tid & 31;   // n-quad
    const int j0 = tid >> 5;  // 0..7
    const float* src = input + (size_t)b * CDIM * HW + n0 + q * 4;
    char* bsb = (char*)&Bs[0][0];
#pragma unroll 4
    for (int j = j0; j < CDIM; j += 8) {
      f32x4 v = *(const f32x4*)(src + (size_t)j * HW);
      unsigned int p0 = pack_rne(v[0], v[1]);
      unsigned int p1 = pack_rne(v[2], v[3]);
      const int byte = j * 260 + q * 8;
      *(unsigned int*)(bsb + byte) = p0;
      *(unsigned int*)(bsb + byte + 4) = p1;
    }
  }
  __syncthreads();

  f32x4 acc[3][8];
#pragma unroll
  for (int t = 0; t < 3; t++)
#pragma unroll
    for (int j = 0; j < 8; j++) acc[t][j] = (f32x4){0.f, 0.f, 0.f, 0.f};

  const unsigned short* Pb = Pbf + (size_t)b * CDIM * CDIM;
  for (int ks = 0; ks < 192; ks += 32) {
    short8 afr[3];
#pragma unroll
    for (int t = 0; t < 3; t++)
      afr[t] = *(const short8*)(Pb + (size_t)(row0 + t * 16 + l15) * CDIM + ks + lg * 8);
#pragma unroll
    for (int tn = 0; tn < 8; tn++) {
      S8U bf;
#pragma unroll
      for (int e2 = 0; e2 < 4; e2++) {
        const int k = ks + lg * 8 + e2 * 2;
        unsigned int h0 = Bs[k][tn * 16 + l15];
        unsigned int h1 = Bs[k + 1][tn * 16 + l15];
        bf.u[e2] = h0 | (h1 << 16);
      }
#pragma unroll
      for (int t = 0; t < 3; t++) acc[t][tn] = MFMA16(afr[t], bf.s, acc[t][tn]);
    }
  }
  float* ob = out + (size_t)b * CDIM * HW + n0;
#pragma unroll
  for (int t = 0; t < 3; t++)
#pragma unroll
    for (int tn = 0; tn < 8; tn++)
#pragma unroll
      for (int r = 0; r < 4; r++) {
        const int m = row0 + t * 16 + lg * 4 + r;
        ob[(size_t)m * HW + tn * 16 + l15] = acc[t][tn][r];
      }
}

// ---------------- launch ----------------
extern "C" void kernel_launch(void* const* d_in, const int* in_sizes, int n_in,
                              void* d_out, int out_size, void* d_ws, size_t ws_size,
                              hipStream_t stream) {
  const float* input = (const float*)d_in[0];
  const float* color = (const float*)d_in[1];
  const float* Wq = (const float*)d_in[2];
  const float* Wk = (const float*)d_in[3];
  const float* Wv = (const float*)d_in[4];
  const float* Wo = (const float*)d_in[5];
  float* out = (float*)d_out;
  char* ws = (char*)d_ws;

  const size_t OFF_G = 0;                        // 3*8*192*192*4 = 3538944
  const size_t OFF_APRE = 3538944;               // 8*192*192*4  = 1179648
  const size_t OFF_NQK = OFF_APRE + 1179648;     // 2*8*192*4    = 12288
  const size_t OFF_ATT = OFF_NQK + 12288;        // 8*8*24*24*4  = 147456
  const size_t OFF_WVT = OFF_ATT + 147456;       // 192*192*2    = 73728
  const size_t OFF_PBF = OFF_WVT + 73728;        // 8*192*192*2  = 589824

  float* G = (float*)(ws + OFF_G);
  float* A_pre = (float*)(ws + OFF_APRE);
  float* nqk = (float*)(ws + OFF_NQK);
  float* attnw = (float*)(ws + OFF_ATT);
  unsigned short* WvT = (unsigned short*)(ws + OFF_WVT);
  unsigned short* Pbf = (unsigned short*)(ws + OFF_PBF);

  hipMemsetAsync(G, 0, 3 * NB * CDIM * CDIM * sizeof(float), stream);
  k0_wvt<<<dim3(144), dim3(256), 0, stream>>>(Wv, WvT);
  gram_k<<<dim3(NSTRIP, NB, 2), dim3(256), 0, stream>>>(input, color, G);
  k2a<<<dim3(NB, 3), dim3(256), 0, stream>>>(G, Wq, Wk, A_pre, nqk);
  k2b<<<dim3(NB), dim3(256), 0, stream>>>(A_pre, nqk, attnw);
  k3<<<dim3(NB), dim3(256), 0, stream>>>(attnw, Wo, WvT, Pbf);
  kD<<<dim3(HW / 128, NB), dim3(256), 0, stream>>>(Pbf, input, out);
}